// Round 6
// baseline (659.335 us; speedup 1.0000x reference)
//
#include <hip/hip_runtime.h>

// SelfAttention: x[8,256,64,64] fp32, W[256,256] fp32.
// R6: split-K flash attention (512 blocks = 8b x 32qt x 2 j-halves).
// 4 waves x 32 q-rows; JT=32 double-buffered K-ONLY LDS (32KB);
// V read directly from global xC (L1/L2-resident) into B-fragments ->
// zero LDS bank conflicts, PV is LDS-free. Partials merged in outgemm.
// ws: xT[b][N][C] | xC[b][C][N] | ctxP[2][b][N][C] | Wb | ML[2][b][N] float2

typedef __attribute__((ext_vector_type(8))) short short8;
typedef __attribute__((ext_vector_type(4))) float floatx4;
typedef __attribute__((ext_vector_type(16))) float floatx16;
typedef __attribute__((ext_vector_type(4))) int intx4;

#define N_TOK 4096
#define C_DIM 256
#define JT 32
#define NT 64  // 2048 / JT per half

typedef const __attribute__((address_space(1))) unsigned int g_uint;
typedef __attribute__((address_space(3))) unsigned int lds_uint;

__device__ __forceinline__ void gll16(const void* g, void* l) {
  __builtin_amdgcn_global_load_lds((g_uint*)g, (lds_uint*)l, 16, 0, 0);
}

__device__ __forceinline__ unsigned short f2bf(float f) {
  unsigned int u = __builtin_bit_cast(unsigned int, f);
  u += 0x7fffu + ((u >> 16) & 1u);
  return (unsigned short)(u >> 16);
}
__device__ __forceinline__ float bf2f(unsigned short v) {
  return __builtin_bit_cast(float, (unsigned int)v << 16);
}

__device__ __forceinline__ floatx16 mfma32(short8 a, short8 b, floatx16 c) {
  return __builtin_amdgcn_mfma_f32_32x32x16_bf16(a, b, c, 0, 0, 0);
}
__device__ __forceinline__ floatx4 mfma16(short8 a, short8 b, floatx4 c) {
  return __builtin_amdgcn_mfma_f32_16x16x32_bf16(a, b, c, 0, 0, 0);
}
__device__ __forceinline__ unsigned cvtpk(float lo, float hi) {
  unsigned d;
  asm("v_cvt_pk_bf16_f32 %0, %1, %2" : "=v"(d) : "v"(lo), "v"(hi));
  return d;
}
__device__ __forceinline__ void swap32(unsigned& a, unsigned& b) {
  asm("v_permlane32_swap_b32 %0, %1" : "+v"(a), "+v"(b));
}

// ---- K1a: x[b][c][i] fp32 -> xT[b][i][c] bf16 and xC[b][c][i] bf16 ----
__global__ __launch_bounds__(256) void transpose_conv(
    const float* __restrict__ x, unsigned short* __restrict__ xT,
    unsigned short* __restrict__ xC) {
  __shared__ float tile[32][33];
  const int b = blockIdx.z;
  const int i0 = blockIdx.x * 32, c0 = blockIdx.y * 32;
  const int tx = threadIdx.x & 31, ty = threadIdx.x >> 5;
  const float* xb = x + (size_t)b * C_DIM * N_TOK;
#pragma unroll
  for (int p = 0; p < 4; ++p) {
    int c = c0 + ty + p * 8;
    float v = xb[(size_t)c * N_TOK + i0 + tx];
    tile[ty + p * 8][tx] = v;
    xC[((size_t)b * C_DIM + c) * N_TOK + i0 + tx] = f2bf(v);
  }
  __syncthreads();
#pragma unroll
  for (int p = 0; p < 4; ++p) {
    int i = i0 + ty + p * 8;
    xT[((size_t)b * N_TOK + i) * C_DIM + c0 + tx] = f2bf(tile[tx][ty + p * 8]);
  }
}

// ---- K1b: W fp32 -> bf16 ----
__global__ __launch_bounds__(256) void wconv(const float* __restrict__ W,
                                             unsigned short* __restrict__ Wb) {
  int idx = blockIdx.x * 256 + threadIdx.x;
  Wb[idx] = f2bf(W[idx]);
}

// ---- K2: split-K flash attention. grid 512, 256 thr ----
// LDS: K tiles only, double-buffered 2x16KB:
//   elem(j,c16) at j*512 + ((c16 ^ (j&7))<<4), j=0..31, c16=0..31
__global__ __launch_bounds__(256, 2) void attn_kernel(
    const unsigned short* __restrict__ xT, const unsigned short* __restrict__ xC,
    unsigned short* __restrict__ ctxP, float2* __restrict__ MLd) {
  const int bid = blockIdx.x;
  const int b = bid & 7;           // batch == XCD -> L2 locality
  const int qt = (bid >> 3) & 31;  // q-tile (128 rows)
  const int g = bid >> 8;          // j-half
  const int tid = threadIdx.x;
  const int lane = tid & 63;
  const int wv = tid >> 6;
  const int l31 = lane & 31;
  const int h = lane >> 5;
  const unsigned short* xTb = xT + (size_t)b * N_TOK * C_DIM;
  const unsigned short* xCb = xC + (size_t)b * N_TOK * C_DIM;
  const char* xTc = (const char*)xTb;
  const int qb = qt * 128 + wv * 32;

  __shared__ char lds[2][16384];

  // staging: linear slots o = i*4096 + wv*1024 + lane*16, inverse-swizzled src
  auto STAGE = [&](int t, int sel) {
    size_t jb = (size_t)(g * 2048 + t * 32);
    char* Kd = lds[sel] + wv * 1024;
#pragma unroll
    for (int i = 0; i < 4; ++i) {
      int j = i * 8 + wv * 2 + (lane >> 5);
      int c16 = (lane & 31) ^ (j & 7);
      gll16(xTc + (jb + j) * 512 + c16 * 16, Kd + i * 4096);
    }
  };

  // Q B-fragments: rows qb+l31, k = ks*16 + h*8 + t
  short8 q[16];
  {
    const unsigned short* qp = xTb + (size_t)(qb + l31) * C_DIM + h * 8;
#pragma unroll
    for (int ks = 0; ks < 16; ++ks) q[ks] = *(const short8*)(qp + ks * 16);
  }

  floatx16 acc[8];
#pragma unroll
  for (int ct = 0; ct < 8; ++ct)
#pragma unroll
    for (int r = 0; r < 16; ++r) acc[ct][r] = 0.f;
  float m = -1e30f, lsum = 0.f;
  const float SC = 0.09016844005556021f;  // log2(e)/16

  STAGE(0, 0);

  for (int t = 0; t < NT; ++t) {
    const int j0 = g * 2048 + t * JT;
    // V B-fragments direct from global xC (L1/L2-resident), issued early:
    // lane(l31,h) ct: vL = xC[ct*32+l31][j0+h*8 ..+7], vH = +16 elems
    short8 vL[8], vH[8];
#pragma unroll
    for (int ct = 0; ct < 8; ++ct) {
      const unsigned short* vp = xCb + (size_t)(ct * 32 + l31) * N_TOK + j0 + h * 8;
      vL[ct] = *(const short8*)(vp);
      vH[ct] = *(const short8*)(vp + 16);
    }
    __syncthreads();  // tile t staged (vmcnt drain); prev-buf reads done
    if (t + 1 < NT) STAGE(t + 1, (t + 1) & 1);
    const char* Kb = lds[t & 1];

    // S^T = mfma(K, Q); lane owns q-row l31 (dup in h)
    floatx16 s;
#pragma unroll
    for (int r = 0; r < 16; ++r) s[r] = 0.f;
    __builtin_amdgcn_s_setprio(1);
#pragma unroll
    for (int ks = 0; ks < 16; ++ks) {
      short8 kf = *(const short8*)(Kb + l31 * 512 + (((2 * ks + h) ^ (l31 & 7)) << 4));
      s = mfma32(kf, q[ks], s);
    }
    __builtin_amdgcn_s_setprio(0);

    // online softmax over 32 j
    float mx = s[0];
#pragma unroll
    for (int r = 1; r < 16; ++r) mx = fmaxf(mx, s[r]);
    mx = fmaxf(mx, __shfl_xor(mx, 32));
    float pm = mx * SC;
    bool need = __any(pm > m + 8.0f) != 0;  // defer-max (T13)
    float mn = need ? fmaxf(m, pm) : m;
    float al = need ? exp2f(m - mn) : 1.0f;
    m = mn;
    float rsum = 0.f;
#pragma unroll
    for (int r = 0; r < 16; ++r) {
      s[r] = exp2f(s[r] * SC - mn);
      rsum += s[r];
    }
    rsum += __shfl_xor(rsum, 32);
    lsum = lsum * al + rsum;
    if (need) {  // wave-uniform, rare after warmup
#pragma unroll
      for (int r = 0; r < 16; ++r) {
        float ar = __shfl(al, (r & 3) + 8 * (r >> 2) + 4 * h);
#pragma unroll
        for (int ct = 0; ct < 8; ++ct) acc[ct][r] *= ar;
      }
    }

    // P^T -> PV A-fragments in-register (cvt_pk + permlane32_swap)
    unsigned pk[8];
#pragma unroll
    for (int pi = 0; pi < 8; ++pi) pk[pi] = cvtpk(s[2 * pi], s[2 * pi + 1]);
    swap32(pk[0], pk[2]); swap32(pk[1], pk[3]);
    swap32(pk[4], pk[6]); swap32(pk[5], pk[7]);
    intx4 a0v = {(int)pk[0], (int)pk[1], (int)pk[2], (int)pk[3]};
    intx4 a1v = {(int)pk[4], (int)pk[5], (int)pk[6], (int)pk[7]};
    short8 pa0 = __builtin_bit_cast(short8, a0v);  // k = j 0..15
    short8 pa1 = __builtin_bit_cast(short8, a1v);  // k = j 16..31

    // O[i][c] += P[i][j] V[j][c]  (V already in registers)
    __builtin_amdgcn_s_setprio(1);
#pragma unroll
    for (int ct = 0; ct < 8; ++ct) {
      acc[ct] = mfma32(pa0, vL[ct], acc[ct]);
      acc[ct] = mfma32(pa1, vH[ct], acc[ct]);
    }
    __builtin_amdgcn_s_setprio(0);
  }

  // epilogue: store partial O (bf16, unnormalized) + (m, l)
  if (h == 0) {
    float2 ml; ml.x = m; ml.y = lsum;
    MLd[((size_t)g * 8 + b) * N_TOK + qb + l31] = ml;
  }
  unsigned short* cb = ctxP + (((size_t)g * 8 + b) * N_TOK + qb) * C_DIM;
#pragma unroll
  for (int r = 0; r < 16; ++r) {
    int ri = (r & 3) + 8 * (r >> 2) + 4 * h;
#pragma unroll
    for (int ct = 0; ct < 8; ++ct)
      cb[(size_t)ri * C_DIM + ct * 32 + l31] = f2bf(acc[ct][r]);
  }
}

// ---- K3: merge halves + out[b][o][i] = (1/l) sum_c W[o][c] ctx[i][c] ----
__global__ __launch_bounds__(256) void outgemm(
    const unsigned short* __restrict__ ctxP, const unsigned short* __restrict__ Wb,
    const float2* __restrict__ MLd, float* __restrict__ out) {
  const int bid = blockIdx.x;
  const int b = bid & 7;
  const int it = bid >> 3;
  const int lane = threadIdx.x & 63;
  const int w = threadIdx.x >> 6;
  const int ibase = it * 64 + w * 16;
  const int l15 = lane & 15, lhi = lane >> 4;
  const unsigned short* c0base = ctxP + (size_t)b * N_TOK * C_DIM;
  const unsigned short* c1base = ctxP + (size_t)(8 + b) * N_TOK * C_DIM;
  const float2* ml0b = MLd + (size_t)b * N_TOK;
  const float2* ml1b = MLd + (size_t)(8 + b) * N_TOK;

  // A-row merge weights (row ia = ibase + l15)
  const int ia = ibase + l15;
  float2 ma = ml0b[ia], mb = ml1b[ia];
  float Ma = fmaxf(ma.x, mb.x);
  float w0 = exp2f(ma.x - Ma), w1 = exp2f(mb.x - Ma);

  // store-row denominators (rows ibase + lhi*4 + r)
  float rden[4];
#pragma unroll
  for (int r = 0; r < 4; ++r) {
    int is = ibase + lhi * 4 + r;
    float2 s0 = ml0b[is], s1 = ml1b[is];
    float Ms = fmaxf(s0.x, s1.x);
    rden[r] = 1.0f / (s0.y * exp2f(s0.x - Ms) + s1.y * exp2f(s1.x - Ms));
  }

  floatx4 acc[16];
#pragma unroll
  for (int i = 0; i < 16; ++i) acc[i] = (floatx4){0.f, 0.f, 0.f, 0.f};

#pragma unroll
  for (int ks = 0; ks < 8; ++ks) {
    short8 o0 = *(const short8*)(c0base + (size_t)ia * C_DIM + ks * 32 + lhi * 8);
    short8 o1 = *(const short8*)(c1base + (size_t)ia * C_DIM + ks * 32 + lhi * 8);
    short8 am;
#pragma unroll
    for (int e = 0; e < 8; ++e)
      am[e] = (short)f2bf(w0 * bf2f((unsigned short)o0[e]) +
                          w1 * bf2f((unsigned short)o1[e]));
#pragma unroll
    for (int ob = 0; ob < 16; ++ob) {
      short8 bw = *(const short8*)(Wb + (size_t)(ob * 16 + l15) * C_DIM + ks * 32 + lhi * 8);
      acc[ob] = mfma16(am, bw, acc[ob]);
    }
  }
  float* outb = out + (size_t)b * C_DIM * N_TOK;
#pragma unroll
  for (int ob = 0; ob < 16; ++ob) {
#pragma unroll
    for (int r = 0; r < 4; ++r) {
      int o = ob * 16 + l15;
      int i = ibase + lhi * 4 + r;
      outb[(size_t)o * N_TOK + i] = acc[ob][r] * rden[r];
    }
  }
}

extern "C" void kernel_launch(void* const* d_in, const int* in_sizes, int n_in,
                              void* d_out, int out_size, void* d_ws, size_t ws_size,
                              hipStream_t stream) {
  const float* x = (const float*)d_in[0];
  const float* W = (const float*)d_in[1];
  float* out = (float*)d_out;
  char* ws = (char*)d_ws;
  const size_t SZ = (size_t)8 * N_TOK * C_DIM * 2;  // 16 MB per bf16 tensor
  unsigned short* xT = (unsigned short*)(ws);
  unsigned short* xC = (unsigned short*)(ws + SZ);
  unsigned short* ctxP = (unsigned short*)(ws + 2 * SZ);          // 32 MB (2 halves)
  unsigned short* Wb = (unsigned short*)(ws + 4 * SZ);            // 128 KB
  float2* MLd = (float2*)(ws + 4 * SZ + C_DIM * C_DIM * 2);       // 512 KB

  hipLaunchKernelGGL(transpose_conv, dim3(N_TOK / 32, C_DIM / 32, 8), dim3(256), 0,
                     stream, x, xT, xC);
  hipLaunchKernelGGL(wconv, dim3((C_DIM * C_DIM) / 256), dim3(256), 0, stream, W, Wb);
  hipLaunchKernelGGL(attn_kernel, dim3(512), dim3(256), 0, stream, xT, xC, ctxP, MLd);
  hipLaunchKernelGGL(outgemm, dim3(512), dim3(256), 0, stream, ctxP, Wb, MLd, out);
}

// Round 7
// 348.589 us; speedup vs baseline: 1.8914x; 1.8914x over previous
//
#include <hip/hip_runtime.h>

// SelfAttention: x[8,256,64,64] fp32, W[256,256] fp32.
// R7: split-K flash attention (512 blocks = 8b x 32qt x 2 j-halves).
// 4 waves x 32 q-rows; JT=32 double-buffered K-ONLY LDS (32KB).
// V read directly from global xC with PADDED pitch (4112 elems = 8224 B,
// odd multiple of 32B -> no L2 set aliasing), loaded inside the PV loop
// (short live range -> no spills). Partials merged in outgemm.
// ws: xT[b][N][C] | xCp[b][C][PITCH] | ctxP[2][b][N][C] | Wb | ML[2][b][N]

typedef __attribute__((ext_vector_type(8))) short short8;
typedef __attribute__((ext_vector_type(4))) float floatx4;
typedef __attribute__((ext_vector_type(16))) float floatx16;
typedef __attribute__((ext_vector_type(4))) int intx4;

#define N_TOK 4096
#define C_DIM 256
#define PITCH 4112  // xC row pitch in elements (8224 B = 32*257, breaks L2 set aliasing)
#define JT 32
#define NT 64  // 2048 / JT per half

typedef const __attribute__((address_space(1))) unsigned int g_uint;
typedef __attribute__((address_space(3))) unsigned int lds_uint;

__device__ __forceinline__ void gll16(const void* g, void* l) {
  __builtin_amdgcn_global_load_lds((g_uint*)g, (lds_uint*)l, 16, 0, 0);
}

__device__ __forceinline__ unsigned short f2bf(float f) {
  unsigned int u = __builtin_bit_cast(unsigned int, f);
  u += 0x7fffu + ((u >> 16) & 1u);
  return (unsigned short)(u >> 16);
}
__device__ __forceinline__ float bf2f(unsigned short v) {
  return __builtin_bit_cast(float, (unsigned int)v << 16);
}

__device__ __forceinline__ floatx16 mfma32(short8 a, short8 b, floatx16 c) {
  return __builtin_amdgcn_mfma_f32_32x32x16_bf16(a, b, c, 0, 0, 0);
}
__device__ __forceinline__ floatx4 mfma16(short8 a, short8 b, floatx4 c) {
  return __builtin_amdgcn_mfma_f32_16x16x32_bf16(a, b, c, 0, 0, 0);
}
__device__ __forceinline__ unsigned cvtpk(float lo, float hi) {
  unsigned d;
  asm("v_cvt_pk_bf16_f32 %0, %1, %2" : "=v"(d) : "v"(lo), "v"(hi));
  return d;
}
__device__ __forceinline__ void swap32(unsigned& a, unsigned& b) {
  asm("v_permlane32_swap_b32 %0, %1" : "+v"(a), "+v"(b));
}

// ---- K1a: x[b][c][i] fp32 -> xT[b][i][c] bf16 and xCp[b][c][i] bf16 ----
__global__ __launch_bounds__(256) void transpose_conv(
    const float* __restrict__ x, unsigned short* __restrict__ xT,
    unsigned short* __restrict__ xC) {
  __shared__ float tile[32][33];
  const int b = blockIdx.z;
  const int i0 = blockIdx.x * 32, c0 = blockIdx.y * 32;
  const int tx = threadIdx.x & 31, ty = threadIdx.x >> 5;
  const float* xb = x + (size_t)b * C_DIM * N_TOK;
#pragma unroll
  for (int p = 0; p < 4; ++p) {
    int c = c0 + ty + p * 8;
    float v = xb[(size_t)c * N_TOK + i0 + tx];
    tile[ty + p * 8][tx] = v;
    xC[((size_t)b * C_DIM + c) * PITCH + i0 + tx] = f2bf(v);
  }
  __syncthreads();
#pragma unroll
  for (int p = 0; p < 4; ++p) {
    int i = i0 + ty + p * 8;
    xT[((size_t)b * N_TOK + i) * C_DIM + c0 + tx] = f2bf(tile[tx][ty + p * 8]);
  }
}

// ---- K1b: W fp32 -> bf16 ----
__global__ __launch_bounds__(256) void wconv(const float* __restrict__ W,
                                             unsigned short* __restrict__ Wb) {
  int idx = blockIdx.x * 256 + threadIdx.x;
  Wb[idx] = f2bf(W[idx]);
}

// ---- K2: split-K flash attention. grid 512, 256 thr, 2 blocks/CU ----
// LDS: K tiles only, double-buffered 2x16KB:
//   elem(j,c16) at j*512 + ((c16 ^ (j&7))<<4), j=0..31, c16=0..31
__global__ __launch_bounds__(256, 2) void attn_kernel(
    const unsigned short* __restrict__ xT, const unsigned short* __restrict__ xC,
    unsigned short* __restrict__ ctxP, float2* __restrict__ MLd) {
  const int bid = blockIdx.x;
  const int b = bid & 7;           // batch == XCD -> L2 locality
  const int qt = (bid >> 3) & 31;  // q-tile (128 rows)
  const int g = bid >> 8;          // j-half
  const int tid = threadIdx.x;
  const int lane = tid & 63;
  const int wv = tid >> 6;
  const int l31 = lane & 31;
  const int h = lane >> 5;
  const unsigned short* xTb = xT + (size_t)b * N_TOK * C_DIM;
  const unsigned short* xCb = xC + (size_t)b * C_DIM * PITCH;
  const char* xTc = (const char*)xTb;
  const int qb = qt * 128 + wv * 32;

  __shared__ char lds[2][16384];

  // staging: linear slots o = i*4096 + wv*1024 + lane*16, inverse-swizzled src
  auto STAGE = [&](int t, int sel) {
    size_t jb = (size_t)(g * 2048 + t * 32);
    char* Kd = lds[sel] + wv * 1024;
#pragma unroll
    for (int i = 0; i < 4; ++i) {
      int j = i * 8 + wv * 2 + (lane >> 5);
      int c16 = (lane & 31) ^ (j & 7);
      gll16(xTc + (jb + j) * 512 + c16 * 16, Kd + i * 4096);
    }
  };

  // Q B-fragments: rows qb+l31, k = ks*16 + h*8 + t
  short8 q[16];
  {
    const unsigned short* qp = xTb + (size_t)(qb + l31) * C_DIM + h * 8;
#pragma unroll
    for (int ks = 0; ks < 16; ++ks) q[ks] = *(const short8*)(qp + ks * 16);
  }

  floatx16 acc[8];
#pragma unroll
  for (int ct = 0; ct < 8; ++ct)
#pragma unroll
    for (int r = 0; r < 16; ++r) acc[ct][r] = 0.f;
  float m = -1e30f, lsum = 0.f;
  const float SC = 0.09016844005556021f;  // log2(e)/16

  STAGE(0, 0);

  for (int t = 0; t < NT; ++t) {
    const int j0 = g * 2048 + t * JT;
    __syncthreads();  // tile t staged (vmcnt drain); prev-buf reads done
    if (t + 1 < NT) STAGE(t + 1, (t + 1) & 1);
    const char* Kb = lds[t & 1];

    // S^T = mfma(K, Q); lane owns q-row l31 (dup in h)
    floatx16 s;
#pragma unroll
    for (int r = 0; r < 16; ++r) s[r] = 0.f;
    __builtin_amdgcn_s_setprio(1);
#pragma unroll
    for (int ks = 0; ks < 16; ++ks) {
      short8 kf = *(const short8*)(Kb + l31 * 512 + (((2 * ks + h) ^ (l31 & 7)) << 4));
      s = mfma32(kf, q[ks], s);
    }
    __builtin_amdgcn_s_setprio(0);

    // online softmax over 32 j
    float mx = s[0];
#pragma unroll
    for (int r = 1; r < 16; ++r) mx = fmaxf(mx, s[r]);
    mx = fmaxf(mx, __shfl_xor(mx, 32));
    float pm = mx * SC;
    bool need = __any(pm > m + 8.0f) != 0;  // defer-max (T13)
    float mn = need ? fmaxf(m, pm) : m;
    float al = need ? exp2f(m - mn) : 1.0f;
    m = mn;
    float rsum = 0.f;
#pragma unroll
    for (int r = 0; r < 16; ++r) {
      s[r] = exp2f(s[r] * SC - mn);
      rsum += s[r];
    }
    rsum += __shfl_xor(rsum, 32);
    lsum = lsum * al + rsum;
    if (need) {  // wave-uniform, rare after warmup
#pragma unroll
      for (int r = 0; r < 16; ++r) {
        float ar = __shfl(al, (r & 3) + 8 * (r >> 2) + 4 * h);
#pragma unroll
        for (int ct = 0; ct < 8; ++ct) acc[ct][r] *= ar;
      }
    }

    // P^T -> PV A-fragments in-register (cvt_pk + permlane32_swap)
    unsigned pk[8];
#pragma unroll
    for (int pi = 0; pi < 8; ++pi) pk[pi] = cvtpk(s[2 * pi], s[2 * pi + 1]);
    swap32(pk[0], pk[2]); swap32(pk[1], pk[3]);
    swap32(pk[4], pk[6]); swap32(pk[5], pk[7]);
    intx4 a0v = {(int)pk[0], (int)pk[1], (int)pk[2], (int)pk[3]};
    intx4 a1v = {(int)pk[4], (int)pk[5], (int)pk[6], (int)pk[7]};
    short8 pa0 = __builtin_bit_cast(short8, a0v);  // k = j 0..15
    short8 pa1 = __builtin_bit_cast(short8, a1v);  // k = j 16..31

    // O[i][c] += P[i][j] V[j][c]; V loaded from padded xC (L1/L2-hit),
    // short live range (consumed by the next 2 MFMAs)
    __builtin_amdgcn_s_setprio(1);
#pragma unroll
    for (int ct = 0; ct < 8; ++ct) {
      const unsigned short* vp = xCb + (size_t)(ct * 32 + l31) * PITCH + j0 + h * 8;
      short8 v0 = *(const short8*)(vp);
      short8 v1 = *(const short8*)(vp + 16);
      acc[ct] = mfma32(pa0, v0, acc[ct]);
      acc[ct] = mfma32(pa1, v1, acc[ct]);
    }
    __builtin_amdgcn_s_setprio(0);
  }

  // epilogue: store partial O (bf16, unnormalized) + (m, l)
  if (h == 0) {
    float2 ml; ml.x = m; ml.y = lsum;
    MLd[((size_t)g * 8 + b) * N_TOK + qb + l31] = ml;
  }
  unsigned short* cb = ctxP + (((size_t)g * 8 + b) * N_TOK + qb) * C_DIM;
#pragma unroll
  for (int r = 0; r < 16; ++r) {
    int ri = (r & 3) + 8 * (r >> 2) + 4 * h;
#pragma unroll
    for (int ct = 0; ct < 8; ++ct)
      cb[(size_t)ri * C_DIM + ct * 32 + l31] = f2bf(acc[ct][r]);
  }
}

// ---- K3: merge halves + out[b][o][i] = (1/l) sum_c W[o][c] ctx[i][c] ----
__global__ __launch_bounds__(256) void outgemm(
    const unsigned short* __restrict__ ctxP, const unsigned short* __restrict__ Wb,
    const float2* __restrict__ MLd, float* __restrict__ out) {
  const int bid = blockIdx.x;
  const int b = bid & 7;
  const int it = bid >> 3;
  const int lane = threadIdx.x & 63;
  const int w = threadIdx.x >> 6;
  const int ibase = it * 64 + w * 16;
  const int l15 = lane & 15, lhi = lane >> 4;
  const unsigned short* c0base = ctxP + (size_t)b * N_TOK * C_DIM;
  const unsigned short* c1base = ctxP + (size_t)(8 + b) * N_TOK * C_DIM;
  const float2* ml0b = MLd + (size_t)b * N_TOK;
  const float2* ml1b = MLd + (size_t)(8 + b) * N_TOK;

  // A-row merge weights (row ia = ibase + l15)
  const int ia = ibase + l15;
  float2 ma = ml0b[ia], mb = ml1b[ia];
  float Ma = fmaxf(ma.x, mb.x);
  float w0 = exp2f(ma.x - Ma), w1 = exp2f(mb.x - Ma);

  // store-row denominators (rows ibase + lhi*4 + r)
  float rden[4];
#pragma unroll
  for (int r = 0; r < 4; ++r) {
    int is = ibase + lhi * 4 + r;
    float2 s0 = ml0b[is], s1 = ml1b[is];
    float Ms = fmaxf(s0.x, s1.x);
    rden[r] = 1.0f / (s0.y * exp2f(s0.x - Ms) + s1.y * exp2f(s1.x - Ms));
  }

  floatx4 acc[16];
#pragma unroll
  for (int i = 0; i < 16; ++i) acc[i] = (floatx4){0.f, 0.f, 0.f, 0.f};

#pragma unroll
  for (int ks = 0; ks < 8; ++ks) {
    short8 o0 = *(const short8*)(c0base + (size_t)ia * C_DIM + ks * 32 + lhi * 8);
    short8 o1 = *(const short8*)(c1base + (size_t)ia * C_DIM + ks * 32 + lhi * 8);
    short8 am;
#pragma unroll
    for (int e = 0; e < 8; ++e)
      am[e] = (short)f2bf(w0 * bf2f((unsigned short)o0[e]) +
                          w1 * bf2f((unsigned short)o1[e]));
#pragma unroll
    for (int ob = 0; ob < 16; ++ob) {
      short8 bw = *(const short8*)(Wb + (size_t)(ob * 16 + l15) * C_DIM + ks * 32 + lhi * 8);
      acc[ob] = mfma16(am, bw, acc[ob]);
    }
  }
  float* outb = out + (size_t)b * C_DIM * N_TOK;
#pragma unroll
  for (int ob = 0; ob < 16; ++ob) {
#pragma unroll
    for (int r = 0; r < 4; ++r) {
      int o = ob * 16 + l15;
      int i = ibase + lhi * 4 + r;
      outb[(size_t)o * N_TOK + i] = acc[ob][r] * rden[r];
    }
  }
}

extern "C" void kernel_launch(void* const* d_in, const int* in_sizes, int n_in,
                              void* d_out, int out_size, void* d_ws, size_t ws_size,
                              hipStream_t stream) {
  const float* x = (const float*)d_in[0];
  const float* W = (const float*)d_in[1];
  float* out = (float*)d_out;
  char* ws = (char*)d_ws;
  const size_t SZ = (size_t)8 * N_TOK * C_DIM * 2;     // 16 MB bf16 [b][N][C]
  const size_t XCSZ = (size_t)8 * C_DIM * PITCH * 2;   // padded xC
  unsigned short* xT = (unsigned short*)(ws);
  unsigned short* xC = (unsigned short*)(ws + SZ);
  unsigned short* ctxP = (unsigned short*)(ws + SZ + XCSZ);             // 32 MB
  unsigned short* Wb = (unsigned short*)(ws + 3 * SZ + XCSZ);           // 128 KB
  float2* MLd = (float2*)(ws + 3 * SZ + XCSZ + C_DIM * C_DIM * 2);      // 512 KB

  hipLaunchKernelGGL(transpose_conv, dim3(N_TOK / 32, C_DIM / 32, 8), dim3(256), 0,
                     stream, x, xT, xC);
  hipLaunchKernelGGL(wconv, dim3((C_DIM * C_DIM) / 256), dim3(256), 0, stream, W, Wb);
  hipLaunchKernelGGL(attn_kernel, dim3(512), dim3(256), 0, stream, xT, xC, ctxP, MLd);
  hipLaunchKernelGGL(outgemm, dim3(512), dim3(256), 0, stream, ctxP, Wb, MLd, out);
}

// Round 8
// 244.447 us; speedup vs baseline: 2.6973x; 1.4260x over previous
//
#include <hip/hip_runtime.h>

// SelfAttention: x[8,256,64,64] fp32, W[256,256] fp32.
// R8: R5 structure + T15 cross-iteration pipeline:
//   iter t: stage K(t+1),V(t); [QK(t) 1:1-interleaved with PV(t-1)]; softmax(t).
// 512 blocks = 8b x 32qt x 2 j-halves; 4 waves x 32 q-rows; JT=32;
// K+V LDS double-buffered (64KB -> 2 blocks/CU). Partials merged in outgemm.
// ws: xT[b][N][C] | xC[b][C][N] | ctxP[2][b][N][C] | Wb | ML[2][b][N] float2

typedef __attribute__((ext_vector_type(8))) short short8;
typedef __attribute__((ext_vector_type(4))) float floatx4;
typedef __attribute__((ext_vector_type(16))) float floatx16;
typedef __attribute__((ext_vector_type(4))) int intx4;

#define N_TOK 4096
#define C_DIM 256
#define JT 32
#define NT 64  // 2048 / JT per half

typedef const __attribute__((address_space(1))) unsigned int g_uint;
typedef __attribute__((address_space(3))) unsigned int lds_uint;

__device__ __forceinline__ void gll16(const void* g, void* l) {
  __builtin_amdgcn_global_load_lds((g_uint*)g, (lds_uint*)l, 16, 0, 0);
}

__device__ __forceinline__ unsigned short f2bf(float f) {
  unsigned int u = __builtin_bit_cast(unsigned int, f);
  u += 0x7fffu + ((u >> 16) & 1u);
  return (unsigned short)(u >> 16);
}
__device__ __forceinline__ float bf2f(unsigned short v) {
  return __builtin_bit_cast(float, (unsigned int)v << 16);
}

__device__ __forceinline__ floatx16 mfma32(short8 a, short8 b, floatx16 c) {
  return __builtin_amdgcn_mfma_f32_32x32x16_bf16(a, b, c, 0, 0, 0);
}
__device__ __forceinline__ floatx4 mfma16(short8 a, short8 b, floatx4 c) {
  return __builtin_amdgcn_mfma_f32_16x16x32_bf16(a, b, c, 0, 0, 0);
}
__device__ __forceinline__ unsigned cvtpk(float lo, float hi) {
  unsigned d;
  asm("v_cvt_pk_bf16_f32 %0, %1, %2" : "=v"(d) : "v"(lo), "v"(hi));
  return d;
}
__device__ __forceinline__ void swap32(unsigned& a, unsigned& b) {
  asm("v_permlane32_swap_b32 %0, %1" : "+v"(a), "+v"(b));
}

// ---- K1a: x[b][c][i] fp32 -> xT[b][i][c] bf16 and xC[b][c][i] bf16 ----
__global__ __launch_bounds__(256) void transpose_conv(
    const float* __restrict__ x, unsigned short* __restrict__ xT,
    unsigned short* __restrict__ xC) {
  __shared__ float tile[32][33];
  const int b = blockIdx.z;
  const int i0 = blockIdx.x * 32, c0 = blockIdx.y * 32;
  const int tx = threadIdx.x & 31, ty = threadIdx.x >> 5;
  const float* xb = x + (size_t)b * C_DIM * N_TOK;
#pragma unroll
  for (int p = 0; p < 4; ++p) {
    int c = c0 + ty + p * 8;
    float v = xb[(size_t)c * N_TOK + i0 + tx];
    tile[ty + p * 8][tx] = v;
    xC[((size_t)b * C_DIM + c) * N_TOK + i0 + tx] = f2bf(v);
  }
  __syncthreads();
#pragma unroll
  for (int p = 0; p < 4; ++p) {
    int i = i0 + ty + p * 8;
    xT[((size_t)b * N_TOK + i) * C_DIM + c0 + tx] = f2bf(tile[tx][ty + p * 8]);
  }
}

// ---- K1b: W fp32 -> bf16 ----
__global__ __launch_bounds__(256) void wconv(const float* __restrict__ W,
                                             unsigned short* __restrict__ Wb) {
  int idx = blockIdx.x * 256 + threadIdx.x;
  Wb[idx] = f2bf(W[idx]);
}

// ---- K2: split-K flash attention. grid 512, 256 thr, 2 blocks/CU ----
// LDS buffer (32KB each, x2):
//   K [0,16KB):   elem(j,c16) at j*512 + ((c16 ^ (j&7))<<4)        j=0..31
//   V [16KB,32KB): paired rows [128r][128B]: elem(c,jc) at
//                  (c>>1)*128 + (((jc | ((c&1)<<2)) ^ ((c>>1)&7))<<4), jc=0..3
__global__ __launch_bounds__(256, 2) void attn_kernel(
    const unsigned short* __restrict__ xT, const unsigned short* __restrict__ xC,
    unsigned short* __restrict__ ctxP, float2* __restrict__ MLd) {
  const int bid = blockIdx.x;
  const int b = bid & 7;           // batch == XCD -> L2 locality
  const int qt = (bid >> 3) & 31;  // q-tile (128 rows)
  const int g = bid >> 8;          // j-half
  const int tid = threadIdx.x;
  const int lane = tid & 63;
  const int wv = tid >> 6;
  const int l31 = lane & 31;
  const int h = lane >> 5;
  const unsigned short* xTb = xT + (size_t)b * N_TOK * C_DIM;
  const unsigned short* xCb = xC + (size_t)b * N_TOK * C_DIM;
  const char* xTc = (const char*)xTb;
  const char* xCc = (const char*)xCb;
  const int qb = qt * 128 + wv * 32;

  __shared__ char lds[2][32768];

  // staging: linear slots o = i*4096 + wv*1024 + lane*16, inverse-swizzled src
  auto STAGE_K = [&](int t, int sel) {
    size_t jb = (size_t)(g * 2048 + t * 32);
    char* Kd = lds[sel] + wv * 1024;
#pragma unroll
    for (int i = 0; i < 4; ++i) {
      int j = i * 8 + wv * 2 + (lane >> 5);
      int c16 = (lane & 31) ^ (j & 7);
      gll16(xTc + (jb + j) * 512 + c16 * 16, Kd + i * 4096);
    }
  };
  auto STAGE_V = [&](int t, int sel) {
    size_t jb = (size_t)(g * 2048 + t * 32);
    char* Vd = lds[sel] + 16384 + wv * 1024;
#pragma unroll
    for (int i = 0; i < 4; ++i) {
      int r = i * 32 + wv * 8 + (lane >> 3);
      int e = (lane & 7) ^ (r & 7);
      int c = 2 * r + (e >> 2);
      gll16(xCc + (size_t)c * 8192 + jb * 2 + (e & 3) * 16, Vd + i * 4096);
    }
  };

  // Q B-fragments: rows qb+l31, k = ks*16 + h*8 + t
  short8 q[16];
  {
    const unsigned short* qp = xTb + (size_t)(qb + l31) * C_DIM + h * 8;
#pragma unroll
    for (int ks = 0; ks < 16; ++ks) q[ks] = *(const short8*)(qp + ks * 16);
  }

  floatx16 acc[8];
#pragma unroll
  for (int ct = 0; ct < 8; ++ct)
#pragma unroll
    for (int r = 0; r < 16; ++r) acc[ct][r] = 0.f;
  float m = -1e30f, lsum = 0.f;
  const float SC = 0.09016844005556021f;  // log2(e)/16

  // prologue: K(0) -> Kb[0]; zero V region of buf 1 (PV(-1) reads zeros)
  STAGE_K(0, 0);
  {
    float4 z = {0.f, 0.f, 0.f, 0.f};
    float4* vz = (float4*)(lds[1] + 16384);
#pragma unroll
    for (int i = 0; i < 4; ++i) vz[tid + i * 256] = z;
  }
  short8 paA0{}, paA1{};  // zero: PV(-1) contributes exactly 0

  // V-read address helpers (R5 layout)
  const int vc = l31;  // c = ct*32 + l31

  for (int t = 0; t < NT; ++t) {
    __syncthreads();  // K(t), V(t-1) staged; prior reads of target bufs done
    if (t + 1 < NT) STAGE_K(t + 1, (t + 1) & 1);
    STAGE_V(t, t & 1);
    const char* Kb = lds[t & 1];
    const char* Vb = lds[(t + 1) & 1] + 16384;  // V(t-1) parity

    // fused phase: QK(t) 1:1 interleaved with PV(t-1)
    floatx16 s;
#pragma unroll
    for (int r = 0; r < 16; ++r) s[r] = 0.f;
    __builtin_amdgcn_s_setprio(1);
#pragma unroll
    for (int i = 0; i < 16; ++i) {
      short8 kf = *(const short8*)(Kb + l31 * 512 + (((2 * i + h) ^ (l31 & 7)) << 4));
      s = mfma32(kf, q[i], s);
      const int ct = i >> 1;
      const int c = ct * 32 + vc;
      const int r = c >> 1;
      const int pb = (c & 1) << 2;
      const int r7 = r & 7;
      if ((i & 1) == 0) {
        short8 v0 = *(const short8*)(Vb + r * 128 + (((h | pb) ^ r7) << 4));
        acc[ct] = mfma32(paA0, v0, acc[ct]);
      } else {
        short8 v1 = *(const short8*)(Vb + r * 128 + ((((2 + h) | pb) ^ r7) << 4));
        acc[ct] = mfma32(paA1, v1, acc[ct]);
      }
    }
    __builtin_amdgcn_s_setprio(0);

    // softmax(t) over 32 j; rescale acc (PV(t-1) already accumulated)
    float mx = s[0];
#pragma unroll
    for (int r = 1; r < 16; ++r) mx = fmaxf(mx, s[r]);
    mx = fmaxf(mx, __shfl_xor(mx, 32));
    float pm = mx * SC;
    bool need = __any(pm > m + 8.0f) != 0;  // defer-max (T13)
    float mn = need ? fmaxf(m, pm) : m;
    float al = need ? exp2f(m - mn) : 1.0f;
    m = mn;
    float rsum = 0.f;
#pragma unroll
    for (int r = 0; r < 16; ++r) {
      s[r] = exp2f(s[r] * SC - mn);
      rsum += s[r];
    }
    rsum += __shfl_xor(rsum, 32);
    lsum = lsum * al + rsum;
    if (need) {  // wave-uniform, rare after warmup
#pragma unroll
      for (int r = 0; r < 16; ++r) {
        float ar = __shfl(al, (r & 3) + 8 * (r >> 2) + 4 * h);
#pragma unroll
        for (int ct = 0; ct < 8; ++ct) acc[ct][r] *= ar;
      }
    }

    // P^T(t) -> PV A-fragments in-register (cvt_pk + permlane32_swap)
    unsigned pk[8];
#pragma unroll
    for (int pi = 0; pi < 8; ++pi) pk[pi] = cvtpk(s[2 * pi], s[2 * pi + 1]);
    swap32(pk[0], pk[2]); swap32(pk[1], pk[3]);
    swap32(pk[4], pk[6]); swap32(pk[5], pk[7]);
    intx4 a0v = {(int)pk[0], (int)pk[1], (int)pk[2], (int)pk[3]};
    intx4 a1v = {(int)pk[4], (int)pk[5], (int)pk[6], (int)pk[7]};
    paA0 = __builtin_bit_cast(short8, a0v);  // k = j 0..15
    paA1 = __builtin_bit_cast(short8, a1v);  // k = j 16..31
  }

  // drain: PV(NT-1) from Vb[(NT-1)&1]
  __syncthreads();
  {
    const char* Vb = lds[(NT - 1) & 1] + 16384;
    __builtin_amdgcn_s_setprio(1);
#pragma unroll
    for (int ct = 0; ct < 8; ++ct) {
      const int c = ct * 32 + vc;
      const int r = c >> 1;
      const int pb = (c & 1) << 2;
      const int r7 = r & 7;
      short8 v0 = *(const short8*)(Vb + r * 128 + (((h | pb) ^ r7) << 4));
      short8 v1 = *(const short8*)(Vb + r * 128 + ((((2 + h) | pb) ^ r7) << 4));
      acc[ct] = mfma32(paA0, v0, acc[ct]);
      acc[ct] = mfma32(paA1, v1, acc[ct]);
    }
    __builtin_amdgcn_s_setprio(0);
  }

  // epilogue: store partial O (bf16, unnormalized) + (m, l)
  if (h == 0) {
    float2 ml; ml.x = m; ml.y = lsum;
    MLd[((size_t)g * 8 + b) * N_TOK + qb + l31] = ml;
  }
  unsigned short* cb = ctxP + (((size_t)g * 8 + b) * N_TOK + qb) * C_DIM;
#pragma unroll
  for (int r = 0; r < 16; ++r) {
    int ri = (r & 3) + 8 * (r >> 2) + 4 * h;
#pragma unroll
    for (int ct = 0; ct < 8; ++ct)
      cb[(size_t)ri * C_DIM + ct * 32 + l31] = f2bf(acc[ct][r]);
  }
}

// ---- K3: merge halves + out[b][o][i] = (1/l) sum_c W[o][c] ctx[i][c] ----
__global__ __launch_bounds__(256) void outgemm(
    const unsigned short* __restrict__ ctxP, const unsigned short* __restrict__ Wb,
    const float2* __restrict__ MLd, float* __restrict__ out) {
  const int bid = blockIdx.x;
  const int b = bid & 7;
  const int it = bid >> 3;
  const int lane = threadIdx.x & 63;
  const int w = threadIdx.x >> 6;
  const int ibase = it * 64 + w * 16;
  const int l15 = lane & 15, lhi = lane >> 4;
  const unsigned short* c0base = ctxP + (size_t)b * N_TOK * C_DIM;
  const unsigned short* c1base = ctxP + (size_t)(8 + b) * N_TOK * C_DIM;
  const float2* ml0b = MLd + (size_t)b * N_TOK;
  const float2* ml1b = MLd + (size_t)(8 + b) * N_TOK;

  // A-row merge weights (row ia = ibase + l15)
  const int ia = ibase + l15;
  float2 ma = ml0b[ia], mb = ml1b[ia];
  float Ma = fmaxf(ma.x, mb.x);
  float w0 = exp2f(ma.x - Ma), w1 = exp2f(mb.x - Ma);

  // store-row denominators (rows ibase + lhi*4 + r)
  float rden[4];
#pragma unroll
  for (int r = 0; r < 4; ++r) {
    int is = ibase + lhi * 4 + r;
    float2 s0 = ml0b[is], s1 = ml1b[is];
    float Ms = fmaxf(s0.x, s1.x);
    rden[r] = 1.0f / (s0.y * exp2f(s0.x - Ms) + s1.y * exp2f(s1.x - Ms));
  }

  floatx4 acc[16];
#pragma unroll
  for (int i = 0; i < 16; ++i) acc[i] = (floatx4){0.f, 0.f, 0.f, 0.f};

#pragma unroll
  for (int ks = 0; ks < 8; ++ks) {
    short8 o0 = *(const short8*)(c0base + (size_t)ia * C_DIM + ks * 32 + lhi * 8);
    short8 o1 = *(const short8*)(c1base + (size_t)ia * C_DIM + ks * 32 + lhi * 8);
    short8 am;
#pragma unroll
    for (int e = 0; e < 8; ++e)
      am[e] = (short)f2bf(w0 * bf2f((unsigned short)o0[e]) +
                          w1 * bf2f((unsigned short)o1[e]));
#pragma unroll
    for (int ob = 0; ob < 16; ++ob) {
      short8 bw = *(const short8*)(Wb + (size_t)(ob * 16 + l15) * C_DIM + ks * 32 + lhi * 8);
      acc[ob] = mfma16(am, bw, acc[ob]);
    }
  }
  float* outb = out + (size_t)b * C_DIM * N_TOK;
#pragma unroll
  for (int ob = 0; ob < 16; ++ob) {
#pragma unroll
    for (int r = 0; r < 4; ++r) {
      int o = ob * 16 + l15;
      int i = ibase + lhi * 4 + r;
      outb[(size_t)o * N_TOK + i] = acc[ob][r] * rden[r];
    }
  }
}

extern "C" void kernel_launch(void* const* d_in, const int* in_sizes, int n_in,
                              void* d_out, int out_size, void* d_ws, size_t ws_size,
                              hipStream_t stream) {
  const float* x = (const float*)d_in[0];
  const float* W = (const float*)d_in[1];
  float* out = (float*)d_out;
  char* ws = (char*)d_ws;
  const size_t SZ = (size_t)8 * N_TOK * C_DIM * 2;  // 16 MB per bf16 tensor
  unsigned short* xT = (unsigned short*)(ws);
  unsigned short* xC = (unsigned short*)(ws + SZ);
  unsigned short* ctxP = (unsigned short*)(ws + 2 * SZ);          // 32 MB (2 halves)
  unsigned short* Wb = (unsigned short*)(ws + 4 * SZ);            // 128 KB
  float2* MLd = (float2*)(ws + 4 * SZ + C_DIM * C_DIM * 2);       // 512 KB

  hipLaunchKernelGGL(transpose_conv, dim3(N_TOK / 32, C_DIM / 32, 8), dim3(256), 0,
                     stream, x, xT, xC);
  hipLaunchKernelGGL(wconv, dim3((C_DIM * C_DIM) / 256), dim3(256), 0, stream, W, Wb);
  hipLaunchKernelGGL(attn_kernel, dim3(512), dim3(256), 0, stream, xT, xC, ctxP, MLd);
  hipLaunchKernelGGL(outgemm, dim3(512), dim3(256), 0, stream, ctxP, Wb, MLd, out);
}